// Round 17
// baseline (327.147 us; speedup 1.0000x reference)
//
#include <hip/hip_runtime.h>
#include <hip/hip_bf16.h>

// BLSTM: B=1024, T=512, V=128, H=128, HH=64, gates=256/dir.
// R17: R16 (249.5us rec, absmax 9.766e-4) + issue diet, bit-identical math:
//  1. tab addressing: xs2 pre-scaled to BYTE offsets (v<<10), per-lane c0b,
//     uniform char* base -> 1 v_add + s-base global_load per gather (was
//     add+shift+64-bit addr math).
//  2. time-index induction (tcur += tstep) + padded xs2 rows at both ends:
//     kills the per-step dir-select and end-clamp cndmask chain.
//  3. gate pre-scales packed into v_pk_mul_f32 (sign flip commutes through
//     fp multiply exactly).
// Oracle: absmax must stay EXACTLY 9.765625e-4.
// Skeleton (R9-R16): MB=8, 8 waves, 1 lgkm-barrier/step, pure-bf16 gate GEMM
// (4 MFMAs), conflict-free A-frag h layout, DPP xor8, duplicated M-rows (no
// xor32), rcp/exp2 transcendentals, one sigma-chain per lane.

#define T_STEPS 512
#define BATCH   1024
#define VOCAB   128
#define HID     128
#define HH      64
#define NG      256
#define MB      8      // real batch rows per block

#define L2E  1.4426950408889634f
#define L2E2 2.8853900817779268f

typedef __attribute__((ext_vector_type(8))) short bf16x8;
typedef __attribute__((ext_vector_type(4))) float f32x4;
typedef __attribute__((ext_vector_type(2))) float f32x2;
typedef unsigned int  u32;
typedef unsigned short u16;

__device__ __forceinline__ float sigmoid_f(float x) {
    return __builtin_amdgcn_rcpf(1.0f + __builtin_amdgcn_exp2f(-x * L2E));
}
__device__ __forceinline__ float tanh_f(float x) {
    return 1.0f - 2.0f * __builtin_amdgcn_rcpf(1.0f + __builtin_amdgcn_exp2f(x * L2E2));
}
__device__ __forceinline__ u16 f2bf_rne(float f) {
    u32 u = __builtin_bit_cast(u32, f);
    u += 0x7FFFu + ((u >> 16) & 1u);
    return (u16)(u >> 16);
}
// lane^8 within each 16-lane row == DPP row_ror:8 (VALU, no DS round trip)
__device__ __forceinline__ float dpp_xor8(float v) {
    int i = __builtin_bit_cast(int, v);
    i = __builtin_amdgcn_mov_dpp(i, 0x128, 0xF, 0xF, true);
    return __builtin_bit_cast(float, i);
}
// barrier with LDS-only drain: h produce/consume needs lgkmcnt(0)+s_barrier;
// global (tab) loads are NOT drained — their waitcnt lands at the use point.
__device__ __forceinline__ void barrier_lgkm() {
    asm volatile("s_waitcnt lgkmcnt(0)\n\ts_barrier" ::: "memory");
}

// permuted gate column c (0..255) -> original gate row g
__device__ __forceinline__ int perm_gate(int c) {
    int tile = c >> 7, rest = c & 127, w = rest >> 4, m = rest & 15;
    return (m < 8) ? (tile * 128 + w * 8 + m)
                   : (tile * 128 + 64 + w * 8 + (m - 8));
}

// ---------------- Kernel 1: tab build + W_hh bf16 convert (fused) ----------
__global__ __launch_bounds__(256) void build_tab_kernel(
    const float* __restrict__ emb,
    const float* __restrict__ W_ih_f,
    const float* __restrict__ W_ih_b,
    const float* __restrict__ W_hh_f,
    const float* __restrict__ W_hh_b,
    float* __restrict__ tab2,
    u16*   __restrict__ whh_bf)
{
    int v = blockIdx.x, d = blockIdx.y, gp = threadIdx.x;
    int tile = gp >> 7, c0 = gp & 127;
    int g = perm_gate(tile * 128 + c0);
    const float* W = d ? W_ih_b : W_ih_f;
    const float4* e4 = (const float4*)(emb + v * HID);
    const float4* w4 = (const float4*)(W + g * HID);
    float acc = 0.0f;
#pragma unroll
    for (int k = 0; k < HID / 4; ++k) {
        float4 e = e4[k]; float4 w = w4[k];
        acc += e.x * w.x + e.y * w.y + e.z * w.z + e.w * w.w;
    }
    tab2[((d * VOCAB + v) * 128 + c0) * 2 + tile] = acc;

    // fused W_hh convert: (d, v) block covers elems [(d*128+v)*128, +128)
    if (gp < 128) {
        const float* Whh = d ? W_hh_b : W_hh_f;
        int idx = v * 128 + gp;           // 0..16383 within this dir
        whh_bf[d * NG * HH + idx] = f2bf_rne(Whh[idx]);
    }
}

// ---------------- Kernel 2: MFMA recurrence ----------------
// grid (128,2), block 512 (8 waves), 1 block/CU.
__global__ __launch_bounds__(512, 2) void lstm_rec_kernel(
    const int*  __restrict__ x,        // [1024][512]
    const u16*  __restrict__ whh_bf,   // [2][256][64] bf16 bits (orig order)
    const float* __restrict__ tab2,    // [2][128][128] float2 pairs, permuted
    float* __restrict__ hfin)          // [2][1024][64]
{
    __shared__ u32 xs2[T_STEPS + 2][MB]; // byte offsets (v<<10), padded ends
    __shared__ u16 hbuf[2][1024];        // [pingpong][elem], 4 KB

    const int tid  = threadIdx.x;
    const int lane = tid & 63;
    const int wave = tid >> 6;           // 0..7
    const int quad = lane >> 4;          // 0..3
    const int m    = lane & 15;
    const int dir    = blockIdx.y;
    const int b_base = blockIdx.x * MB;

    // stage x, pre-scaled to tab2 BYTE offset (v * 128 pairs * 8 B = v<<10);
    // logical step t lives at xs2[t+1]; rows 0 and T+1 are pads (values
    // unused: last prefetch is discarded)
    for (int i = tid; i < MB * T_STEPS; i += 512) {
        int bl = i >> 9, t = i & (T_STEPS - 1);
        xs2[t + 1][bl] = ((u32)x[(b_base + bl) * T_STEPS + t]) << 10;
    }
    if (tid < MB) {
        xs2[0][tid]           = ((u32)x[(b_base + tid) * T_STEPS]) << 10;
        xs2[T_STEPS + 1][tid] = ((u32)x[(b_base + tid) * T_STEPS + T_STEPS - 1]) << 10;
    }
    // zero both h buffers (M-rows 8..15 = duplicates, also zeroed)
    for (int i = tid; i < 1024; i += 512) ((u32*)hbuf)[i] = 0;

    // persistent B-fragments, permuted gate rows
    const u16* WB = whh_bf + dir * NG * HH;
    bf16x8 Bh[2][2];
#pragma unroll
    for (int tile = 0; tile < 2; ++tile) {
        int grow = perm_gate(tile * 128 + wave * 16 + m);
#pragma unroll
        for (int kc = 0; kc < 2; ++kc)
            Bh[tile][kc] = *(const bf16x8*)(WB + grow * HH + kc * 32 + quad * 8);
    }

    const char* baseC = (const char*)tab2 + (size_t)dir * VOCAB * 128 * 8;
    const u32  c0b    = (u32)(wave * 16 + m) * 8;   // pair-col byte offset
    const bool lohalf = (m < 8);
    const bool second = (quad >= 2);            // take row r0+1's gate set
    // the ONE real row this lane finalizes in phase B:
    const int  row    = 4 * (quad & 1) + (lohalf ? 0 : 2) + (quad >> 1);
    const int  wbase  = (wave >> 2) * 512 + (wave & 3) * 128 + (m & 7);
    const int  woff   = wbase + row * 8;        // M-row `row`
    const int  woff2  = woff + 64;              // duplicate at M-row row+8
    const int  aoff   = lane * 8;               // u16 units
    const int  xrow   = (quad & 1) * 4;         // xs2 sub-row for my 4 C-rows

    // time induction: t for step s; prefetch advances it
    const int tstep = dir ? -1 : 1;
    int tcur        = dir ? (T_STEPS - 1) : 0;

    float cc = 0.f, hcur = 0.f;
    float I0[4], I1[4], J0[4], J1[4];

    __syncthreads();   // xs2 + hbuf init visible (full barrier once, fine)

    {   // prefetch step 0
        int4 vv = *(const int4*)&xs2[1 + tcur][xrow];
        float2 p0 = *(const float2*)(baseC + ((u32)vv.x + c0b));
        float2 p1 = *(const float2*)(baseC + ((u32)vv.y + c0b));
        float2 p2 = *(const float2*)(baseC + ((u32)vv.z + c0b));
        float2 p3 = *(const float2*)(baseC + ((u32)vv.w + c0b));
        I0[0] = p0.x; I1[0] = p0.y;
        I0[1] = p1.x; I1[1] = p1.y;
        I0[2] = p2.x; I1[2] = p2.y;
        I0[3] = p3.x; I1[3] = p3.y;
    }

    auto step = [&](const u16* rh, u16* wh,
                    float (&cur0)[4], float (&cur1)[4],
                    float (&nx0)[4], float (&nx1)[4]) {
        bf16x8 Ah0 = *(const bf16x8*)(rh + aoff);
        bf16x8 Ah1 = *(const bf16x8*)(rh + 512 + aoff);

        // prefetch next step's tab init (global; vmcnt wait lands at use,
        // NOT at the barrier — barrier_lgkm drains LDS only). Index is pure
        // induction; padded rows absorb the final (discarded) prefetch.
        {
            tcur += tstep;
            int4 vv = *(const int4*)&xs2[1 + tcur][xrow];   // one ds_read_b128
            float2 p0 = *(const float2*)(baseC + ((u32)vv.x + c0b));
            float2 p1 = *(const float2*)(baseC + ((u32)vv.y + c0b));
            float2 p2 = *(const float2*)(baseC + ((u32)vv.z + c0b));
            float2 p3 = *(const float2*)(baseC + ((u32)vv.w + c0b));
            nx0[0] = p0.x; nx1[0] = p0.y;
            nx0[1] = p1.x; nx1[1] = p1.y;
            nx0[2] = p2.x; nx1[2] = p2.y;
            nx0[3] = p3.x; nx1[3] = p3.y;
        }

        // pure-bf16 gate GEMM: 4 MFMAs, dependent depth 2.
        // A rows 8..15 duplicate rows 0..7 -> C rows 8..15 are bit-exact
        // duplicates: quads 2,3 natively hold real gate values.
        f32x4 acc0 = {cur0[0], cur0[1], cur0[2], cur0[3]};
        f32x4 acc1 = {cur1[0], cur1[1], cur1[2], cur1[3]};
        acc0 = __builtin_amdgcn_mfma_f32_16x16x32_bf16(Ah0, Bh[0][0], acc0, 0, 0, 0);
        acc1 = __builtin_amdgcn_mfma_f32_16x16x32_bf16(Ah0, Bh[1][0], acc1, 0, 0, 0);
        acc0 = __builtin_amdgcn_mfma_f32_16x16x32_bf16(Ah1, Bh[0][1], acc0, 0, 0, 0);
        acc1 = __builtin_amdgcn_mfma_f32_16x16x32_bf16(Ah1, Bh[1][1], acc1, 0, 0, 0);

        // xor8 exchange via DPP (VALU): complete (i,f,g,o) for my 2 C rows
        float e0 = dpp_xor8(lohalf ? acc0[2] : acc0[0]);
        float e1 = dpp_xor8(lohalf ? acc0[3] : acc0[1]);
        float e2 = dpp_xor8(lohalf ? acc1[2] : acc1[0]);
        float e3 = dpp_xor8(lohalf ? acc1[3] : acc1[1]);

        float i0 = lohalf ? acc0[0] : e0;    // row r0
        float f0 = lohalf ? e0 : acc0[2];
        float g0 = lohalf ? acc1[0] : e2;
        float o0 = lohalf ? e2 : acc1[2];
        float i1 = lohalf ? acc0[1] : e1;    // row r0+1
        float f1 = lohalf ? e1 : acc0[3];
        float g1 = lohalf ? acc1[1] : e3;
        float o1 = lohalf ? e3 : acc1[3];

        // row select (no lane traffic): quads 2,3 keep duplicated row r0+1
        float gi = second ? i1 : i0;
        float gf = second ? f1 : f0;
        float gg = second ? g1 : g0;
        float go = second ? o1 : o0;

        // packed pre-scale (bit-exact: x*(-L2E) == -(x*L2E) in IEEE)
        f32x2 sif = f32x2{gi, gf} * f32x2{-L2E, -L2E};    // v_pk_mul_f32
        float Ei = __builtin_amdgcn_exp2f(sif.x);
        float Ef = __builtin_amdgcn_exp2f(sif.y);
        float Eg = __builtin_amdgcn_exp2f(gg * L2E2);
        float Eo = __builtin_amdgcn_exp2f(-(go * L2E));
        float si = __builtin_amdgcn_rcpf(1.0f + Ei);
        float sf = __builtin_amdgcn_rcpf(1.0f + Ef);
        float tg = 1.0f - 2.0f * __builtin_amdgcn_rcpf(1.0f + Eg);
        float so = __builtin_amdgcn_rcpf(1.0f + Eo);

        cc   = sf * cc + si * tg;
        hcur = so * tanh_f(cc);

        u16 hb = f2bf_rne(hcur);
        wh[woff]  = hb;        // M-row `row`
        wh[woff2] = hb;        // duplicate at M-row row+8
    };

    for (int it = 0; it < T_STEPS / 2; ++it) {
        step(hbuf[0], hbuf[1], I0, I1, J0, J1);
        barrier_lgkm();
        step(hbuf[1], hbuf[0], J0, J1, I0, I1);
        barrier_lgkm();
    }

    // every thread owns exactly one (b, j)
    {
        int j = wave * 8 + (m & 7);
        hfin[(dir * BATCH + b_base + row) * HH + j] = hcur;
    }
}

// ---------------- Kernel 3: final FC (W_fc in LDS, 8 rows/block) ----------
__global__ __launch_bounds__(256) void fc_kernel(
    const float* __restrict__ hfin,    // [2][1024][64]
    const float* __restrict__ W_fc,    // [128][128]
    const float* __restrict__ b_fc,    // [128]
    float* __restrict__ out)           // [1024][128]
{
    __shared__ float wfc[HID * 129];   // row-padded: bank stride 129
    __shared__ float hid[8][HID];
    const int tid = threadIdx.x;
    const int b0  = blockIdx.x * 8;

    for (int i = tid; i < HID * HID; i += 256) {
        int r = i >> 7, c = i & 127;
        wfc[r * 129 + c] = W_fc[i];
    }
    for (int i = tid; i < 8 * HID; i += 256) {
        int bb = i >> 7, v = i & 127;
        hid[bb][v] = (v < HH) ? hfin[(0 * BATCH + b0 + bb) * HH + v]
                              : hfin[(1 * BATCH + b0 + bb) * HH + (v - HH)];
    }
    __syncthreads();

    const int v  = tid & 127;
    const int bs = (tid >> 7) * 4;     // rows [bs, bs+4)
    const float bias = b_fc[v];
    const float* wrow = wfc + v * 129;
#pragma unroll
    for (int r = 0; r < 4; ++r) {
        const float* h = hid[bs + r];
        float acc = bias;
#pragma unroll
        for (int k = 0; k < HID; k += 4) {
            acc += wrow[k]     * h[k]     + wrow[k + 1] * h[k + 1]
                 + wrow[k + 2] * h[k + 2] + wrow[k + 3] * h[k + 3];
        }
        out[(b0 + bs + r) * HID + v] = acc;
    }
}

extern "C" void kernel_launch(void* const* d_in, const int* in_sizes, int n_in,
                              void* d_out, int out_size, void* d_ws, size_t ws_size,
                              hipStream_t stream) {
    const int*   x      = (const int*)d_in[0];
    // d_in[1] = lengths : unused by the reference
    const float* emb    = (const float*)d_in[2];
    const float* W_ih_f = (const float*)d_in[3];
    const float* W_hh_f = (const float*)d_in[4];
    const float* W_ih_b = (const float*)d_in[5];
    const float* W_hh_b = (const float*)d_in[6];
    const float* W_fc   = (const float*)d_in[7];
    const float* b_fc   = (const float*)d_in[8];
    float* out = (float*)d_out;

    float* tab2   = (float*)d_ws;                         // 65536 f32 (pairs)
    u16*   whh_bf = (u16*)(tab2 + 2 * VOCAB * NG);        // 32768 u16
    float* hfin   = (float*)(whh_bf + 2 * NG * HH);       // 131072 f32

    build_tab_kernel<<<dim3(VOCAB, 2), 256, 0, stream>>>(
        emb, W_ih_f, W_ih_b, W_hh_f, W_hh_b, tab2, whh_bf);
    lstm_rec_kernel<<<dim3(BATCH / MB, 2), 512, 0, stream>>>(x, whh_bf, tab2, hfin);
    fc_kernel<<<dim3(BATCH / 8), 256, 0, stream>>>(hfin, W_fc, b_fc, out);
}